// Round 1
// baseline (474.787 us; speedup 1.0000x reference)
//
#include <hip/hip_runtime.h>
#include <hip/hip_bf16.h>
#include <cstdint>

// Problem constants (B,S,E,H) = (4, 2048, 256, 8), fp32 in/out.
#define B_N 4
#define S_N 2048
#define E_N 256
#define H_N 8

typedef float f32x4 __attribute__((ext_vector_type(4)));
typedef short s16x8 __attribute__((ext_vector_type(8)));   // 8 bf16 as shorts (4 VGPR)

static __device__ __forceinline__ f32x4 mfma16(s16x8 a, s16x8 b, f32x4 c) {
  return __builtin_amdgcn_mfma_f32_16x16x32_bf16(a, b, c, 0, 0, 0);
}

// fp32 <-> bf16 (RNE) without class types (keeps LDS arrays POD).
static __device__ __forceinline__ unsigned short f2bf(float f) {
  union { float f; unsigned int u; } v; v.f = f;
  unsigned int r = v.u + 0x7fffu + ((v.u >> 16) & 1u);
  return (unsigned short)(r >> 16);
}
static __device__ __forceinline__ float bf2f(unsigned short s) {
  union { unsigned int u; float f; } v; v.u = ((unsigned int)s) << 16;
  return v.f;
}

// ---------------------------------------------------------------------------
// Split fp32 -> bf16 hi + bf16 lo  (hi = rne(x), lo = rne(x - hi)); vec x4.
__global__ void k_split(const float* __restrict__ src, unsigned short* __restrict__ hi,
                        unsigned short* __restrict__ lo, int n4) {
  int i = blockIdx.x * blockDim.x + threadIdx.x;
  if (i >= n4) return;
  float4 v = ((const float4*)src)[i];
  float f[4] = {v.x, v.y, v.z, v.w};
  unsigned short hh[4], ll[4];
#pragma unroll
  for (int j = 0; j < 4; j++) {
    hh[j] = f2bf(f[j]);
    ll[j] = f2bf(f[j] - bf2f(hh[j]));
  }
  ushort4 h; h.x = hh[0]; h.y = hh[1]; h.z = hh[2]; h.w = hh[3];
  ushort4 l; l.x = ll[0]; l.y = ll[1]; l.z = ll[2]; l.w = ll[3];
  ((ushort4*)hi)[i] = h;
  ((ushort4*)lo)[i] = l;
}

// ---------------------------------------------------------------------------
// WvT[h][f][e] = bf16(Wv[h][e][f])   (32x32 LDS tile transpose)
__global__ void k_transpose_wv(const float* __restrict__ wv, unsigned short* __restrict__ wvT) {
  __shared__ float t[32][33];
  int h = blockIdx.z;
  int e0 = blockIdx.x * 32, f0 = blockIdx.y * 32;
  int tx = threadIdx.x & 31, ty = threadIdx.x >> 5;
  const float* src = wv + ((size_t)h * E_N + e0) * E_N + f0;
#pragma unroll
  for (int r = ty; r < 32; r += 8) t[r][tx] = src[(size_t)r * E_N + tx];
  __syncthreads();
  unsigned short* dst = wvT + ((size_t)h * E_N + f0) * E_N + e0;
#pragma unroll
  for (int r = ty; r < 32; r += 8) dst[(size_t)r * E_N + tx] = f2bf(t[tx][r]);
}

// ---------------------------------------------------------------------------
// bt-GEMM: C[m,n] = sum_k A[m,k]*B[n,k], 128x128 tile, BK=32, 4 waves.
// TERMS==3: A,B are split (hi,lo): acc += Ah*Bh + Ah*Bl + Al*Bh (split-precision).
// SPLIT_OUT: write C as bf16 hi+lo pair, else plain bf16.
// Batch z: operand offset = ((z/div)%mod)*stride.
#define BKP 40  // 32 + 8 pad: keeps 16B alignment, 2-way max bank conflict

template <int TERMS, int SPLIT_OUT>
__global__ __launch_bounds__(256, 2) void k_gemm(
    const unsigned short* __restrict__ Ahi, const unsigned short* __restrict__ Alo,
    const unsigned short* __restrict__ Bhi, const unsigned short* __restrict__ Blo,
    unsigned short* __restrict__ Chi, unsigned short* __restrict__ Clo,
    int K, int N,
    int aDiv, int aMod, long long aStr,
    int bDiv, int bMod, long long bStr,
    long long cStr) {
  __shared__ unsigned short sA[2][128 * BKP];
  __shared__ unsigned short sB[2][128 * BKP];
  int z = blockIdx.z;
  const unsigned short* A0h = Ahi + (long long)((z / aDiv) % aMod) * aStr;
  const unsigned short* A0l = Alo + (long long)((z / aDiv) % aMod) * aStr;
  const unsigned short* B0h = Bhi + (long long)((z / bDiv) % bMod) * bStr;
  const unsigned short* B0l = Blo + (long long)((z / bDiv) % bMod) * bStr;
  int rT = blockIdx.x * 128, cT = blockIdx.y * 128;
  int tid = threadIdx.x;
  int w = tid >> 6, l = tid & 63, lr = l & 15, lg = l >> 4;
  int wr = w >> 1, wc = w & 1;

  f32x4 acc[4][4];
#pragma unroll
  for (int i = 0; i < 4; i++)
#pragma unroll
    for (int j = 0; j < 4; j++) acc[i][j] = (f32x4){0.f, 0.f, 0.f, 0.f};

  for (int k0 = 0; k0 < K; k0 += 32) {
#pragma unroll
    for (int it = 0; it < 2; it++) {
      int idx = (it * 256 + tid) * 8;
      int r = idx >> 5, c = idx & 31;
      *(s16x8*)&sA[0][r * BKP + c] = *(const s16x8*)(A0h + (size_t)(rT + r) * K + k0 + c);
      *(s16x8*)&sB[0][r * BKP + c] = *(const s16x8*)(B0h + (size_t)(cT + r) * K + k0 + c);
      if (TERMS == 3) {
        *(s16x8*)&sA[1][r * BKP + c] = *(const s16x8*)(A0l + (size_t)(rT + r) * K + k0 + c);
        *(s16x8*)&sB[1][r * BKP + c] = *(const s16x8*)(B0l + (size_t)(cT + r) * K + k0 + c);
      }
    }
    __syncthreads();
    s16x8 ah[4], al[4], bh[4], bl[4];
#pragma unroll
    for (int i = 0; i < 4; i++) {
      ah[i] = *(const s16x8*)&sA[0][(wr * 64 + i * 16 + lr) * BKP + lg * 8];
      if (TERMS == 3) al[i] = *(const s16x8*)&sA[1][(wr * 64 + i * 16 + lr) * BKP + lg * 8];
    }
#pragma unroll
    for (int j = 0; j < 4; j++) {
      bh[j] = *(const s16x8*)&sB[0][(wc * 64 + j * 16 + lr) * BKP + lg * 8];
      if (TERMS == 3) bl[j] = *(const s16x8*)&sB[1][(wc * 64 + j * 16 + lr) * BKP + lg * 8];
    }
#pragma unroll
    for (int i = 0; i < 4; i++)
#pragma unroll
      for (int j = 0; j < 4; j++) {
        acc[i][j] = mfma16(ah[i], bh[j], acc[i][j]);
        if (TERMS == 3) {
          acc[i][j] = mfma16(ah[i], bl[j], acc[i][j]);
          acc[i][j] = mfma16(al[i], bh[j], acc[i][j]);
        }
      }
    __syncthreads();
  }
  long long cOff = (long long)z * cStr;
#pragma unroll
  for (int i = 0; i < 4; i++)
#pragma unroll
    for (int j = 0; j < 4; j++)
#pragma unroll
      for (int r = 0; r < 4; r++) {
        int row = rT + wr * 64 + i * 16 + lg * 4 + r;  // C/D: row=(l>>4)*4+reg
        int col = cT + wc * 64 + j * 16 + lr;          //      col=l&15
        float v = acc[i][j][r];
        unsigned short hb = f2bf(v);
        Chi[cOff + (size_t)row * N + col] = hb;
        if (SPLIT_OUT) Clo[cOff + (size_t)row * N + col] = f2bf(v - bf2f(hb));
      }
}

// ---------------------------------------------------------------------------
// Fused flash attention: per block (qt, bh): 128 q-rows (8 waves x 16),
// loop over 32 kv-tiles of TT=64. logits = Y . X^T (3-term split), online
// softmax (fp32), P -> LDS bf16, O += P . VT (bt-form). Head-mean via
// atomicAdd * 1/8 into zeroed d_out.
#define TT 64
#define XPAD 264  // 256+8 (16B-aligned rows, 2-way max conflict)
#define VPAD 72   // 64+8
#define PPAD 72
#define ATTN_LDS (2 * TT * XPAD * 2 + 256 * VPAD * 2 + 8 * 16 * PPAD * 2)  // 122880 B

__global__ __launch_bounds__(512, 2) void k_attn(
    const unsigned short* __restrict__ Yhi, const unsigned short* __restrict__ Ylo,
    const unsigned short* __restrict__ Xhi, const unsigned short* __restrict__ Xlo,
    const unsigned short* __restrict__ VT, float* __restrict__ Out) {
  extern __shared__ unsigned short smem[];
  unsigned short* sXhi = smem;                  // [TT][XPAD]
  unsigned short* sXlo = sXhi + TT * XPAD;      // [TT][XPAD]
  unsigned short* sVT = sXlo + TT * XPAD;       // [256][VPAD]
  unsigned short* sP = sVT + 256 * VPAD;        // [8][16][PPAD]

  int qt = blockIdx.x, bh = blockIdx.y;
  int b = bh >> 3;
  int tid = threadIdx.x, w = tid >> 6, l = tid & 63, lr = l & 15, lg = l >> 4;
  const unsigned short* Ybh_h = Yhi + (size_t)bh * S_N * E_N;
  const unsigned short* Ybh_l = Ylo + (size_t)bh * S_N * E_N;
  const unsigned short* Xb_h = Xhi + (size_t)b * S_N * E_N;
  const unsigned short* Xb_l = Xlo + (size_t)b * S_N * E_N;
  const unsigned short* Vbh = VT + (size_t)bh * E_N * S_N;
  int qrow = qt * 128 + w * 16;

  // Hoist Y fragments (A-operand, 16 rows x K=256, hi+lo) into registers.
  s16x8 yh[8], yl[8];
#pragma unroll
  for (int kc = 0; kc < 8; kc++) {
    yh[kc] = *(const s16x8*)(Ybh_h + (size_t)(qrow + lr) * E_N + kc * 32 + lg * 8);
    yl[kc] = *(const s16x8*)(Ybh_l + (size_t)(qrow + lr) * E_N + kc * 32 + lg * 8);
  }
  f32x4 o[16];
#pragma unroll
  for (int i = 0; i < 16; i++) o[i] = (f32x4){0.f, 0.f, 0.f, 0.f};
  float mrun[4], lrun[4];
#pragma unroll
  for (int r = 0; r < 4; r++) { mrun[r] = -3.0e38f; lrun[r] = 0.f; }

  for (int kt = 0; kt < S_N / TT; kt++) {
    // Stage X(hi,lo) [64][256] and VT [256][64] tiles (reg-staged, padded LDS).
#pragma unroll
    for (int it = 0; it < 4; it++) {
      int idx = (it * 512 + tid) * 8;
      int r = idx >> 8, c = idx & 255;
      *(s16x8*)&sXhi[r * XPAD + c] = *(const s16x8*)(Xb_h + (size_t)(kt * TT + r) * E_N + c);
      *(s16x8*)&sXlo[r * XPAD + c] = *(const s16x8*)(Xb_l + (size_t)(kt * TT + r) * E_N + c);
      int rv = idx >> 6, cv = idx & 63;
      *(s16x8*)&sVT[rv * VPAD + cv] = *(const s16x8*)(Vbh + (size_t)rv * S_N + kt * TT + cv);
    }
    __syncthreads();

    // S = Y . X^T (3-term split), 4 col-frags of 16 t-cols.
    f32x4 sc[4];
#pragma unroll
    for (int j = 0; j < 4; j++) {
      f32x4 a = (f32x4){0.f, 0.f, 0.f, 0.f};
#pragma unroll
      for (int kc = 0; kc < 8; kc++) {
        s16x8 xh = *(const s16x8*)&sXhi[(j * 16 + lr) * XPAD + kc * 32 + lg * 8];
        s16x8 xl = *(const s16x8*)&sXlo[(j * 16 + lr) * XPAD + kc * 32 + lg * 8];
        a = mfma16(yh[kc], xh, a);
        a = mfma16(yh[kc], xl, a);
        a = mfma16(yl[kc], xh, a);
      }
      sc[j] = a * 0.0625f;  // scale = 1/sqrt(E)
    }

    // Online softmax update. Lane holds rows lg*4+r, col lr (+16j).
    float tmax[4];
#pragma unroll
    for (int r = 0; r < 4; r++)
      tmax[r] = fmaxf(fmaxf(sc[0][r], sc[1][r]), fmaxf(sc[2][r], sc[3][r]));
#pragma unroll
    for (int off = 1; off < 16; off <<= 1)
#pragma unroll
      for (int r = 0; r < 4; r++) tmax[r] = fmaxf(tmax[r], __shfl_xor(tmax[r], off, 64));

    float newm[4], fr[4], p[4][4], rs[4];
#pragma unroll
    for (int r = 0; r < 4; r++) {
      newm[r] = fmaxf(mrun[r], tmax[r]);
      fr[r] = exp2f((mrun[r] - newm[r]) * 1.4426950408889634f);
    }
#pragma unroll
    for (int j = 0; j < 4; j++)
#pragma unroll
      for (int r = 0; r < 4; r++)
        p[j][r] = exp2f((sc[j][r] - newm[r]) * 1.4426950408889634f);
#pragma unroll
    for (int r = 0; r < 4; r++) rs[r] = ((p[0][r] + p[1][r]) + (p[2][r] + p[3][r]));
#pragma unroll
    for (int off = 1; off < 16; off <<= 1)
#pragma unroll
      for (int r = 0; r < 4; r++) rs[r] += __shfl_xor(rs[r], off, 64);
#pragma unroll
    for (int r = 0; r < 4; r++) {
      lrun[r] = lrun[r] * fr[r] + rs[r];
      mrun[r] = newm[r];
    }
#pragma unroll
    for (int i = 0; i < 16; i++)
#pragma unroll
      for (int r = 0; r < 4; r++) o[i][r] *= fr[r];

    // P -> LDS (per-wave buffer; same-wave dep, compiler inserts lgkmcnt).
    unsigned short* sPw = sP + w * 16 * PPAD;
#pragma unroll
    for (int j = 0; j < 4; j++)
#pragma unroll
      for (int r = 0; r < 4; r++)
        sPw[(lg * 4 + r) * PPAD + j * 16 + lr] = f2bf(p[j][r]);

    // O += P . VT  (bt-form: A=P[16 rows][64 t], B=VT[f][t])
#pragma unroll
    for (int tc = 0; tc < 2; tc++) {
      s16x8 pa = *(const s16x8*)&sPw[lr * PPAD + tc * 32 + lg * 8];
#pragma unroll
      for (int jf = 0; jf < 16; jf++) {
        s16x8 bv = *(const s16x8*)&sVT[(jf * 16 + lr) * VPAD + tc * 32 + lg * 8];
        o[jf] = mfma16(pa, bv, o[jf]);
      }
    }
    __syncthreads();
  }

  // Epilogue: normalize rows, head-mean via atomics.
#pragma unroll
  for (int jf = 0; jf < 16; jf++)
#pragma unroll
    for (int r = 0; r < 4; r++) {
      float v = o[jf][r] / lrun[r] * 0.125f;
      atomicAdd(&Out[((size_t)b * S_N + qrow + lg * 4 + r) * E_N + jf * 16 + lr], v);
    }
}

// ---------------------------------------------------------------------------
extern "C" void kernel_launch(void* const* d_in, const int* in_sizes, int n_in,
                              void* d_out, int out_size, void* d_ws, size_t ws_size,
                              hipStream_t stream) {
  const float* x = (const float*)d_in[0];
  const float* wq = (const float*)d_in[1];
  const float* wk = (const float*)d_in[2];
  const float* wv = (const float*)d_in[3];
  float* out = (float*)d_out;

  // Workspace layout (bf16 elements; total ~111 MB).
  unsigned short* ws = (unsigned short*)d_ws;
  unsigned short* x_hi = ws;                       // [B,S,E]
  unsigned short* x_lo = x_hi + 2097152;
  unsigned short* wq_hi = x_lo + 2097152;          // [H,E,E]
  unsigned short* wq_lo = wq_hi + 524288;
  unsigned short* wk_hi = wq_lo + 524288;
  unsigned short* wk_lo = wk_hi + 524288;
  unsigned short* wvT = wk_lo + 524288;            // [H,E(f),E(e)]
  unsigned short* mt_hi = wvT + 524288;            // [H,E(e'),E(e)] = Wk.Wq^T
  unsigned short* mt_lo = mt_hi + 524288;
  unsigned short* y_hi = mt_lo + 524288;           // [B,H,S,E]
  unsigned short* y_lo = y_hi + 16777216;
  unsigned short* vt = y_lo + 16777216;            // [B,H,E(f),S(t)]

  hipMemsetAsync(d_out, 0, (size_t)out_size * sizeof(float), stream);

  k_split<<<2048, 256, 0, stream>>>(x, x_hi, x_lo, 524288);
  k_split<<<512, 256, 0, stream>>>(wq, wq_hi, wq_lo, 131072);
  k_split<<<512, 256, 0, stream>>>(wk, wk_hi, wk_lo, 131072);
  k_transpose_wv<<<dim3(8, 8, 8), 256, 0, stream>>>(wv, wvT);

  // MT_h = Wk_h . Wq_h^T   (z = h)
  k_gemm<3, 1><<<dim3(2, 2, 8), 256, 0, stream>>>(
      wk_hi, wk_lo, wq_hi, wq_lo, mt_hi, mt_lo, 256, 256,
      1, 8, 65536LL, 1, 8, 65536LL, 65536LL);
  // Y[b,h] = X_b . MT_h^T   (z = b*H+h)
  k_gemm<3, 1><<<dim3(16, 2, 32), 256, 0, stream>>>(
      x_hi, x_lo, mt_hi, mt_lo, y_hi, y_lo, 256, 256,
      8, 4, 524288LL, 1, 8, 65536LL, 524288LL);
  // VT[b,h] = WvT_h . X_b^T  -> [f][t]  (plain bf16)
  k_gemm<1, 0><<<dim3(2, 16, 32), 256, 0, stream>>>(
      wvT, wvT, x_hi, x_hi, vt, vt, 256, 2048,
      1, 8, 65536LL, 8, 4, 524288LL, 524288LL);

  hipFuncSetAttribute((const void*)k_attn, hipFuncAttributeMaxDynamicSharedMemorySize,
                      ATTN_LDS);
  k_attn<<<dim3(16, 32), 512, ATTN_LDS, stream>>>(y_hi, y_lo, x_hi, x_lo, vt, out);
}